// Round 1
// baseline (3445.528 us; speedup 1.0000x reference)
//
#include <hip/hip_runtime.h>

// ---------------------------------------------------------------------------
// Recurrent GraphSAGE net, fp32 baseline.
// Decomposition per timestep:
//   xcat = [x_prev(4) | mesh(8)]                      (N x 12)
//   h1 = relu(agg12(xcat)@Wl1^T + b1 + xcat@Wr1^T)    (N x 128)
//   h2 = relu(agg128(h1)@Wl2^T + b2 + h1@Wr2^T)
//   h1 = relu(agg128(h2)@Wld1^T + bd1 + h2@Wrd1^T)
//   h2 = relu(agg128(h1)@Wld2^T + bd2 + h1@Wrd2^T)
//   x_new = x_prev + h2@linW^T + linb ; out[:,t,:] = x_new ; x_prev = x_new
// CSR (in-edges, grouped by dst) built once per launch.
// ---------------------------------------------------------------------------

__global__ void count_deg_kernel(const int* __restrict__ dst, int* __restrict__ cnt, int E) {
  int e = blockIdx.x * blockDim.x + threadIdx.x;
  if (e < E) atomicAdd(&cnt[dst[e]], 1);
}

__global__ void rdeg_kernel(const int* __restrict__ cnt, float* __restrict__ rdeg, int N) {
  int n = blockIdx.x * blockDim.x + threadIdx.x;
  if (n < N) rdeg[n] = 1.0f / fmaxf((float)cnt[n], 1.0f);
}

__global__ __launch_bounds__(1024) void scan_kernel(const int* __restrict__ cnt,
                                                    int* __restrict__ row_ptr, int n) {
  __shared__ int sdata[1024];
  __shared__ int s_carry;
  int tid = threadIdx.x;
  if (tid == 0) s_carry = 0;
  __syncthreads();
  for (int base = 0; base < n; base += 1024) {
    int i = base + tid;
    int v = (i < n) ? cnt[i] : 0;
    sdata[tid] = v;
    __syncthreads();
    for (int off = 1; off < 1024; off <<= 1) {
      int t = (tid >= off) ? sdata[tid - off] : 0;
      __syncthreads();
      sdata[tid] += t;
      __syncthreads();
    }
    int carry = s_carry;
    if (i < n) row_ptr[i + 1] = carry + sdata[tid];
    __syncthreads();
    if (tid == 1023) s_carry = carry + sdata[1023];
    __syncthreads();
  }
  if (tid == 0) row_ptr[0] = 0;
}

__global__ void fill_csr_kernel(const int* __restrict__ src, const int* __restrict__ dst,
                                const int* __restrict__ row_ptr, int* __restrict__ cursor,
                                int* __restrict__ col, int E) {
  int e = blockIdx.x * blockDim.x + threadIdx.x;
  if (e < E) {
    int d = dst[e];
    int p = atomicAdd(&cursor[d], 1);
    col[row_ptr[d] + p] = src[e];
  }
}

__global__ void build_xcat_kernel(const float* __restrict__ xprev, const float* __restrict__ mesh,
                                  float* __restrict__ xcat, int N) {
  int g = blockIdx.x * blockDim.x + threadIdx.x;
  if (g < N * 12) {
    int n = g / 12, c = g % 12;
    xcat[g] = (c < 4) ? xprev[n * 4 + c] : mesh[n * 8 + (c - 4)];
  }
}

// 16 threads per node (12 active channels)
__global__ void agg12_kernel(const float* __restrict__ feat, float* __restrict__ out,
                             const int* __restrict__ row_ptr, const int* __restrict__ col,
                             const float* __restrict__ rdeg, int N) {
  int g = blockIdx.x * blockDim.x + threadIdx.x;
  int node = g >> 4;
  int d = g & 15;
  if (node >= N || d >= 12) return;
  int j0 = row_ptr[node], j1 = row_ptr[node + 1];
  float acc = 0.0f;
  for (int j = j0; j < j1; ++j) {
    int s = col[j];
    acc += feat[s * 12 + d];
  }
  out[node * 12 + d] = acc * rdeg[node];
}

// 32 threads per node, float4 per lane (512B coalesced row gather)
__global__ void agg128_kernel(const float* __restrict__ feat, float* __restrict__ out,
                              const int* __restrict__ row_ptr, const int* __restrict__ col,
                              const float* __restrict__ rdeg, int N) {
  int g = blockIdx.x * blockDim.x + threadIdx.x;
  int node = g >> 5;
  int d = g & 31;
  if (node >= N) return;
  int j0 = row_ptr[node], j1 = row_ptr[node + 1];
  float4 acc = make_float4(0.f, 0.f, 0.f, 0.f);
  for (int j = j0; j < j1; ++j) {
    int s = col[j];
    float4 v = *(const float4*)&feat[s * 128 + d * 4];
    acc.x += v.x; acc.y += v.y; acc.z += v.z; acc.w += v.w;
  }
  float r = rdeg[node];
  acc.x *= r; acc.y *= r; acc.z *= r; acc.w *= r;
  *(float4*)&out[node * 128 + d * 4] = acc;
}

// enc1 GEMM: out(N x 128) = relu(agg12 @ Wl^T + bl + x12 @ Wr^T), W is 128x12
__global__ __launch_bounds__(256) void gemm12_kernel(
    const float* __restrict__ agg, const float* __restrict__ x,
    const float* __restrict__ Wl, const float* __restrict__ Wr,
    const float* __restrict__ bl, float* __restrict__ out, int N) {
  __shared__ float Ws[24][128];     // [k][o]
  __shared__ float As[16][24];      // [node][k]  (agg | x)
  int tid = threadIdx.x;
  int nb = blockIdx.x * 16;
  for (int i = tid; i < 1536; i += 256) {
    int o = i / 12, k = i % 12;
    Ws[k][o] = Wl[i];
    Ws[12 + k][o] = Wr[i];
  }
  for (int i = tid; i < 192; i += 256) {
    int n = i / 12, k = i % 12;
    int gn = nb + n; if (gn > N - 1) gn = N - 1;
    As[n][k] = agg[gn * 12 + k];
    As[n][12 + k] = x[gn * 12 + k];
  }
  __syncthreads();
  int nl = tid >> 4;     // 0..15
  int og = tid & 15;     // outputs og*8 .. og*8+7
  float acc[8] = {};
#pragma unroll
  for (int k = 0; k < 24; ++k) {
    float a = As[nl][k];
    float4 w0 = *(const float4*)&Ws[k][og * 8];
    float4 w1 = *(const float4*)&Ws[k][og * 8 + 4];
    acc[0] += a * w0.x; acc[1] += a * w0.y; acc[2] += a * w0.z; acc[3] += a * w0.w;
    acc[4] += a * w1.x; acc[5] += a * w1.y; acc[6] += a * w1.z; acc[7] += a * w1.w;
  }
  int gn = nb + nl;
  if (gn < N) {
#pragma unroll
    for (int j = 0; j < 8; ++j) {
      float v = acc[j] + bl[og * 8 + j];
      out[gn * 128 + og * 8 + j] = fmaxf(v, 0.0f);
    }
  }
}

// big conv GEMM: out(N x 128) = relu(agg @ Wl^T + bl + x @ Wr^T), W is 128x128
#define BM 64
__global__ __launch_bounds__(256) void gemm128_kernel(
    const float* __restrict__ agg, const float* __restrict__ x,
    const float* __restrict__ Wl, const float* __restrict__ Wr,
    const float* __restrict__ bl, float* __restrict__ out, int N) {
  __shared__ float As[16][BM + 4];   // [k][node], pad 4 keeps 16B align + spreads banks
  __shared__ float Ws[16][132];      // [k][o]
  int tid = threadIdx.x;
  int nb = blockIdx.x * BM;
  int to = tid & 31;   // outputs to*4 .. to*4+3
  int tn = tid >> 5;   // nodes tn*8 .. tn*8+7
  float acc[8][4] = {};

  for (int c = 0; c < 16; ++c) {
    const float* __restrict__ Asrc = (c < 8) ? agg : x;
    const float* __restrict__ Wsrc = (c < 8) ? Wl : Wr;
    int k0 = (c & 7) * 16;
    {
      int kk = tid & 15;
      int n4 = tid >> 4;
#pragma unroll
      for (int r = 0; r < 4; ++r) {
        int n = n4 + r * 16;
        int gn = nb + n; if (gn > N - 1) gn = N - 1;
        As[kk][n] = Asrc[gn * 128 + k0 + kk];
      }
    }
    {
      int kk = tid & 15;
      int o8 = tid >> 4;
#pragma unroll
      for (int r = 0; r < 8; ++r) {
        int o = o8 + r * 16;
        Ws[kk][o] = Wsrc[o * 128 + k0 + kk];
      }
    }
    __syncthreads();
#pragma unroll
    for (int kk = 0; kk < 16; ++kk) {
      float4 w = *(const float4*)&Ws[kk][to * 4];
      float4 a0 = *(const float4*)&As[kk][tn * 8];
      float4 a1 = *(const float4*)&As[kk][tn * 8 + 4];
      float av[8] = {a0.x, a0.y, a0.z, a0.w, a1.x, a1.y, a1.z, a1.w};
      float wv[4] = {w.x, w.y, w.z, w.w};
#pragma unroll
      for (int i = 0; i < 8; ++i)
#pragma unroll
        for (int j = 0; j < 4; ++j)
          acc[i][j] += av[i] * wv[j];
    }
    __syncthreads();
  }

  float4 bias = *(const float4*)&bl[to * 4];
#pragma unroll
  for (int i = 0; i < 8; ++i) {
    int gn = nb + tn * 8 + i;
    if (gn < N) {
      float4 v;
      v.x = fmaxf(acc[i][0] + bias.x, 0.0f);
      v.y = fmaxf(acc[i][1] + bias.y, 0.0f);
      v.z = fmaxf(acc[i][2] + bias.z, 0.0f);
      v.w = fmaxf(acc[i][3] + bias.w, 0.0f);
      *(float4*)&out[gn * 128 + to * 4] = v;
    }
  }
}

// head: x_new = x_prev + h @ linW^T + linb ; writes out[:,t,:] and updates xprev
__global__ __launch_bounds__(256) void lin_kernel(
    const float* __restrict__ h, const float* __restrict__ linW,
    const float* __restrict__ linb, float* __restrict__ xprev,
    float* __restrict__ out, int N, int T, int t) {
  __shared__ float hs[64][132];
  __shared__ float Wls[4][132];
  int tid = threadIdx.x;
  int nb = blockIdx.x * 64;
  for (int i = tid; i < 512; i += 256) Wls[i >> 7][i & 127] = linW[i];
  for (int i = tid; i < 8192; i += 256) {
    int n = i >> 7, k = i & 127;
    int gn = nb + n; if (gn > N - 1) gn = N - 1;
    hs[n][k] = h[gn * 128 + k];
  }
  __syncthreads();
  int nl = tid >> 2, o = tid & 3;
  float acc = 0.0f;
#pragma unroll 8
  for (int k = 0; k < 128; k += 4) {
    float4 hv = *(const float4*)&hs[nl][k];
    float4 wv = *(const float4*)&Wls[o][k];
    acc += hv.x * wv.x + hv.y * wv.y + hv.z * wv.z + hv.w * wv.w;
  }
  int gn = nb + nl;
  if (gn < N) {
    float v = xprev[gn * 4 + o] + acc + linb[o];
    out[(gn * T + t) * 4 + o] = v;
    xprev[gn * 4 + o] = v;
  }
}

extern "C" void kernel_launch(void* const* d_in, const int* in_sizes, int n_in,
                              void* d_out, int out_size, void* d_ws, size_t ws_size,
                              hipStream_t stream) {
  const float* F0   = (const float*)d_in[0];
  const float* mesh = (const float*)d_in[1];
  const int*   eidx = (const int*)d_in[2];
  const float* e1Wl = (const float*)d_in[4];
  const float* e1bl = (const float*)d_in[5];
  const float* e1Wr = (const float*)d_in[6];
  const float* e2Wl = (const float*)d_in[7];
  const float* e2bl = (const float*)d_in[8];
  const float* e2Wr = (const float*)d_in[9];
  const float* d1Wl = (const float*)d_in[10];
  const float* d1bl = (const float*)d_in[11];
  const float* d1Wr = (const float*)d_in[12];
  const float* d2Wl = (const float*)d_in[13];
  const float* d2bl = (const float*)d_in[14];
  const float* d2Wr = (const float*)d_in[15];
  const float* linW = (const float*)d_in[16];
  const float* linb = (const float*)d_in[17];

  const int N = in_sizes[0] / 4;        // 50000
  const int E = in_sizes[2] / 2;        // 800000
  const int T = out_size / (N * 4);     // 8
  const int* src = eidx;
  const int* dst = eidx + E;

  size_t off = 0;
  auto alloc = [&](size_t bytes) -> void* {
    void* p = (char*)d_ws + off;
    off += (bytes + 511) & ~(size_t)511;
    return p;
  };
  int*   cnt     = (int*)alloc((size_t)N * 4);
  int*   row_ptr = (int*)alloc((size_t)(N + 1) * 4);
  int*   cursor  = (int*)alloc((size_t)N * 4);
  int*   col     = (int*)alloc((size_t)E * 4);
  float* rdeg    = (float*)alloc((size_t)N * 4);
  float* xprev   = (float*)alloc((size_t)N * 4 * 4);
  float* xcat    = (float*)alloc((size_t)N * 12 * 4);
  float* agg12b  = (float*)alloc((size_t)N * 12 * 4);
  float* h1      = (float*)alloc((size_t)N * 128 * 4);
  float* h2      = (float*)alloc((size_t)N * 128 * 4);
  float* aggb    = (float*)alloc((size_t)N * 128 * 4);

  float* outp = (float*)d_out;

  // ---- graph preprocessing (once per launch) ----
  hipMemsetAsync(cnt, 0, (size_t)N * 4, stream);
  hipMemsetAsync(cursor, 0, (size_t)N * 4, stream);
  count_deg_kernel<<<(E + 255) / 256, 256, 0, stream>>>(dst, cnt, E);
  rdeg_kernel<<<(N + 255) / 256, 256, 0, stream>>>(cnt, rdeg, N);
  scan_kernel<<<1, 1024, 0, stream>>>(cnt, row_ptr, N);
  fill_csr_kernel<<<(E + 255) / 256, 256, 0, stream>>>(src, dst, row_ptr, cursor, col, E);

  // x_prev init = F_0 (N x 4)
  hipMemcpyAsync(xprev, F0, (size_t)N * 4 * 4, hipMemcpyDeviceToDevice, stream);

  const int gAgg128 = (N * 32 + 255) / 256;
  const int gAgg12  = (N * 16 + 255) / 256;
  const int gGemm128 = (N + BM - 1) / BM;
  const int gGemm12  = (N + 15) / 16;
  const int gLin     = (N + 63) / 64;

  for (int t = 0; t < T; ++t) {
    build_xcat_kernel<<<(N * 12 + 255) / 256, 256, 0, stream>>>(xprev, mesh, xcat, N);
    agg12_kernel<<<gAgg12, 256, 0, stream>>>(xcat, agg12b, row_ptr, col, rdeg, N);
    gemm12_kernel<<<gGemm12, 256, 0, stream>>>(agg12b, xcat, e1Wl, e1Wr, e1bl, h1, N);

    agg128_kernel<<<gAgg128, 256, 0, stream>>>(h1, aggb, row_ptr, col, rdeg, N);
    gemm128_kernel<<<gGemm128, 256, 0, stream>>>(aggb, h1, e2Wl, e2Wr, e2bl, h2, N);

    agg128_kernel<<<gAgg128, 256, 0, stream>>>(h2, aggb, row_ptr, col, rdeg, N);
    gemm128_kernel<<<gGemm128, 256, 0, stream>>>(aggb, h2, d1Wl, d1Wr, d1bl, h1, N);

    agg128_kernel<<<gAgg128, 256, 0, stream>>>(h1, aggb, row_ptr, col, rdeg, N);
    gemm128_kernel<<<gGemm128, 256, 0, stream>>>(aggb, h1, d2Wl, d2Wr, d2bl, h2, N);

    lin_kernel<<<gLin, 256, 0, stream>>>(h2, linW, linb, xprev, outp, N, T, t);
  }
}

// Round 2
// 2013.371 us; speedup vs baseline: 1.7113x; 1.7113x over previous
//
#include <hip/hip_runtime.h>

// ---------------------------------------------------------------------------
// Recurrent GraphSAGE net. Round 1: bf16 hidden activations + MFMA GEMMs.
//   xcat = [x_prev(4) | mesh(8)]                       (N x 12, fp32)
//   h1 = relu(agg12(xcat)@Wl1^T + b1 + xcat@Wr1^T)     -> bf16 (N x 128)
//   h2 = relu(agg128(h1)@Wl2^T + b2 + h1@Wr2^T)        (bf16 MFMA)
//   h1 = relu(agg128(h2)@Wld1^T + ...)
//   h2 = relu(agg128(h1)@Wld2^T + ...)
//   x_new = x_prev + h2@linW^T + linb  (fp32)
// CSR built once per launch. bf16 halves gather bytes; MFMA for 128x256x128.
// ---------------------------------------------------------------------------

typedef __attribute__((ext_vector_type(8))) short short8;
typedef __attribute__((ext_vector_type(8))) unsigned short ushort8;
typedef __attribute__((ext_vector_type(4))) float f32x4;

static __device__ __forceinline__ float b2f(unsigned short u) {
  return __uint_as_float(((unsigned int)u) << 16);
}
static __device__ __forceinline__ unsigned short f2bf(float f) {
  unsigned int u = __float_as_uint(f);
  u += 0x7FFFu + ((u >> 16) & 1u);   // round-nearest-even
  return (unsigned short)(u >> 16);
}

// ---------------- graph preprocessing ----------------

__global__ void count_deg_kernel(const int* __restrict__ dst, int* __restrict__ cnt, int E) {
  int e = blockIdx.x * blockDim.x + threadIdx.x;
  if (e < E) atomicAdd(&cnt[dst[e]], 1);
}

__global__ void rdeg_kernel(const int* __restrict__ cnt, float* __restrict__ rdeg, int N) {
  int n = blockIdx.x * blockDim.x + threadIdx.x;
  if (n < N) rdeg[n] = 1.0f / fmaxf((float)cnt[n], 1.0f);
}

// serial-per-thread prefix + one 1024-wide ladder (n <= 1024*seg)
__global__ __launch_bounds__(1024) void scan_kernel(const int* __restrict__ cnt,
                                                    int* __restrict__ row_ptr, int n) {
  __shared__ int sums[1024];
  int tid = threadIdx.x;
  int seg = (n + 1023) >> 10;
  int i0 = tid * seg;
  int i1 = i0 + seg; if (i1 > n) i1 = n;
  int s = 0;
  for (int i = i0; i < i1; ++i) s += cnt[i];
  sums[tid] = s;
  __syncthreads();
  for (int off = 1; off < 1024; off <<= 1) {
    int t = (tid >= off) ? sums[tid - off] : 0;
    __syncthreads();
    sums[tid] += t;
    __syncthreads();
  }
  int run = (tid == 0) ? 0 : sums[tid - 1];
  for (int i = i0; i < i1; ++i) { run += cnt[i]; row_ptr[i + 1] = run; }
  if (tid == 0) row_ptr[0] = 0;
}

__global__ void fill_csr_kernel(const int* __restrict__ src, const int* __restrict__ dst,
                                const int* __restrict__ row_ptr, int* __restrict__ cursor,
                                int* __restrict__ col, int E) {
  int e = blockIdx.x * blockDim.x + threadIdx.x;
  if (e < E) {
    int d = dst[e];
    int p = atomicAdd(&cursor[d], 1);
    col[row_ptr[d] + p] = src[e];
  }
}

__global__ void f2bf_kernel(const float* __restrict__ src, unsigned short* __restrict__ dst, int n) {
  int i = blockIdx.x * blockDim.x + threadIdx.x;
  if (i < n) dst[i] = f2bf(src[i]);
}

// ---------------- per-timestep kernels ----------------

__global__ void build_xcat_kernel(const float* __restrict__ xprev, const float* __restrict__ mesh,
                                  float* __restrict__ xcat, int N) {
  int g = blockIdx.x * blockDim.x + threadIdx.x;
  if (g < N * 12) {
    int n = g / 12, c = g % 12;
    xcat[g] = (c < 4) ? xprev[n * 4 + c] : mesh[n * 8 + (c - 4)];
  }
}

// 16 threads per node (12 active channels), fp32 (tiny)
__global__ void agg12_kernel(const float* __restrict__ feat, float* __restrict__ out,
                             const int* __restrict__ row_ptr, const int* __restrict__ col,
                             const float* __restrict__ rdeg, int N) {
  int g = blockIdx.x * blockDim.x + threadIdx.x;
  int node = g >> 4;
  int d = g & 15;
  if (node >= N || d >= 12) return;
  int j0 = row_ptr[node], j1 = row_ptr[node + 1];
  float acc = 0.0f;
  for (int j = j0; j < j1; ++j) acc += feat[col[j] * 12 + d];
  out[node * 12 + d] = acc * rdeg[node];
}

// bf16 mean-aggregate: 16 lanes/node, ushort8 (16B) per lane, fp32 accum
__global__ void agg128_kernel(const unsigned short* __restrict__ feat,
                              unsigned short* __restrict__ out,
                              const int* __restrict__ row_ptr, const int* __restrict__ col,
                              const float* __restrict__ rdeg, int N) {
  int g = blockIdx.x * blockDim.x + threadIdx.x;
  int node = g >> 4;
  int d = g & 15;
  if (node >= N) return;
  int j0 = row_ptr[node], j1 = row_ptr[node + 1];
  float acc[8] = {};
  int j = j0;
  for (; j + 2 <= j1; j += 2) {
    int s0 = col[j], s1 = col[j + 1];
    ushort8 v0 = *(const ushort8*)&feat[s0 * 128 + d * 8];
    ushort8 v1 = *(const ushort8*)&feat[s1 * 128 + d * 8];
#pragma unroll
    for (int r = 0; r < 8; ++r) acc[r] += b2f(v0[r]) + b2f(v1[r]);
  }
  if (j < j1) {
    ushort8 v0 = *(const ushort8*)&feat[col[j] * 128 + d * 8];
#pragma unroll
    for (int r = 0; r < 8; ++r) acc[r] += b2f(v0[r]);
  }
  float rd = rdeg[node];
  ushort8 o;
#pragma unroll
  for (int r = 0; r < 8; ++r) o[r] = f2bf(acc[r] * rd);
  *(ushort8*)&out[node * 128 + d * 8] = o;
}

// enc1 GEMM (K=24, fp32 compute, bf16 output)
__global__ __launch_bounds__(256) void gemm12_kernel(
    const float* __restrict__ agg, const float* __restrict__ x,
    const float* __restrict__ Wl, const float* __restrict__ Wr,
    const float* __restrict__ bl, unsigned short* __restrict__ out, int N) {
  __shared__ float Ws[24][128];
  __shared__ float As[16][24];
  int tid = threadIdx.x;
  int nb = blockIdx.x * 16;
  for (int i = tid; i < 1536; i += 256) {
    int o = i / 12, k = i % 12;
    Ws[k][o] = Wl[i];
    Ws[12 + k][o] = Wr[i];
  }
  for (int i = tid; i < 192; i += 256) {
    int n = i / 12, k = i % 12;
    int gn = nb + n; if (gn > N - 1) gn = N - 1;
    As[n][k] = agg[gn * 12 + k];
    As[n][12 + k] = x[gn * 12 + k];
  }
  __syncthreads();
  int nl = tid >> 4;
  int og = tid & 15;
  float acc[8] = {};
#pragma unroll
  for (int k = 0; k < 24; ++k) {
    float a = As[nl][k];
    float4 w0 = *(const float4*)&Ws[k][og * 8];
    float4 w1 = *(const float4*)&Ws[k][og * 8 + 4];
    acc[0] += a * w0.x; acc[1] += a * w0.y; acc[2] += a * w0.z; acc[3] += a * w0.w;
    acc[4] += a * w1.x; acc[5] += a * w1.y; acc[6] += a * w1.z; acc[7] += a * w1.w;
  }
  int gn = nb + nl;
  if (gn < N) {
#pragma unroll
    for (int j = 0; j < 8; ++j) {
      float v = acc[j] + bl[og * 8 + j];
      out[gn * 128 + og * 8 + j] = f2bf(fmaxf(v, 0.0f));
    }
  }
}

// conv GEMM via MFMA: out(N x128) = relu([agg|x](N x256) @ [Wl;Wr]^T + bl), bf16 in/out
// block = 4 waves, each wave independent: 32 nodes x 128 outs, K=256
__global__ __launch_bounds__(256) void gemm128_mfma_kernel(
    const unsigned short* __restrict__ agg, const unsigned short* __restrict__ x,
    const unsigned short* __restrict__ Wlb, const unsigned short* __restrict__ Wrb,
    const float* __restrict__ bl, unsigned short* __restrict__ out, int N) {
  int tid = threadIdx.x;
  int wave = tid >> 6;
  int lane = tid & 63;
  int nb = blockIdx.x * 128 + wave * 32;
  int l15 = lane & 15;          // A-row / B-col / C-col
  int lk = (lane >> 4) * 8;     // k sub-offset

  f32x4 acc[2][8] = {};
  int r0 = nb + l15;      if (r0 > N - 1) r0 = N - 1;
  int r1 = nb + 16 + l15; if (r1 > N - 1) r1 = N - 1;

#pragma unroll
  for (int ks = 0; ks < 8; ++ks) {
    const unsigned short* As = (ks < 4) ? agg : x;
    const unsigned short* Ws = (ks < 4) ? Wlb : Wrb;
    int ko = (ks & 3) * 32 + lk;
    short8 a0 = *(const short8*)&As[r0 * 128 + ko];
    short8 a1 = *(const short8*)&As[r1 * 128 + ko];
#pragma unroll
    for (int ot = 0; ot < 8; ++ot) {
      short8 b = *(const short8*)&Ws[(ot * 16 + l15) * 128 + ko];
      acc[0][ot] = __builtin_amdgcn_mfma_f32_16x16x32_bf16(a0, b, acc[0][ot], 0, 0, 0);
      acc[1][ot] = __builtin_amdgcn_mfma_f32_16x16x32_bf16(a1, b, acc[1][ot], 0, 0, 0);
    }
  }

  int crow = (lane >> 4) * 4;   // C: col = lane&15, row = (lane>>4)*4 + reg
#pragma unroll
  for (int ot = 0; ot < 8; ++ot) {
    int gcol = ot * 16 + l15;
    float bv = bl[gcol];
#pragma unroll
    for (int mt = 0; mt < 2; ++mt) {
#pragma unroll
      for (int r = 0; r < 4; ++r) {
        int grow = nb + mt * 16 + crow + r;
        if (grow < N) {
          float v = fmaxf(acc[mt][ot][r] + bv, 0.0f);
          out[grow * 128 + gcol] = f2bf(v);
        }
      }
    }
  }
}

// head: x_new = x_prev + h @ linW^T + linb  (h bf16, rest fp32)
__global__ __launch_bounds__(256) void lin_kernel(
    const unsigned short* __restrict__ h, const float* __restrict__ linW,
    const float* __restrict__ linb, float* __restrict__ xprev,
    float* __restrict__ out, int N, int T, int t) {
  __shared__ float hs[64][132];
  __shared__ float Wls[4][132];
  int tid = threadIdx.x;
  int nb = blockIdx.x * 64;
  for (int i = tid; i < 512; i += 256) Wls[i >> 7][i & 127] = linW[i];
  for (int i = tid; i < 1024; i += 256) {
    int n = i >> 4, c = i & 15;
    int gn = nb + n; if (gn > N - 1) gn = N - 1;
    ushort8 v = *(const ushort8*)&h[gn * 128 + c * 8];
#pragma unroll
    for (int r = 0; r < 8; ++r) hs[n][c * 8 + r] = b2f(v[r]);
  }
  __syncthreads();
  int nl = tid >> 2, o = tid & 3;
  float acc = 0.0f;
#pragma unroll 8
  for (int k = 0; k < 128; k += 4) {
    float4 hv = *(const float4*)&hs[nl][k];
    float4 wv = *(const float4*)&Wls[o][k];
    acc += hv.x * wv.x + hv.y * wv.y + hv.z * wv.z + hv.w * wv.w;
  }
  int gn = nb + nl;
  if (gn < N) {
    float v = xprev[gn * 4 + o] + acc + linb[o];
    out[(gn * T + t) * 4 + o] = v;
    xprev[gn * 4 + o] = v;
  }
}

extern "C" void kernel_launch(void* const* d_in, const int* in_sizes, int n_in,
                              void* d_out, int out_size, void* d_ws, size_t ws_size,
                              hipStream_t stream) {
  const float* F0   = (const float*)d_in[0];
  const float* mesh = (const float*)d_in[1];
  const int*   eidx = (const int*)d_in[2];
  const float* e1Wl = (const float*)d_in[4];
  const float* e1bl = (const float*)d_in[5];
  const float* e1Wr = (const float*)d_in[6];
  const float* e2Wl = (const float*)d_in[7];
  const float* e2bl = (const float*)d_in[8];
  const float* e2Wr = (const float*)d_in[9];
  const float* d1Wl = (const float*)d_in[10];
  const float* d1bl = (const float*)d_in[11];
  const float* d1Wr = (const float*)d_in[12];
  const float* d2Wl = (const float*)d_in[13];
  const float* d2bl = (const float*)d_in[14];
  const float* d2Wr = (const float*)d_in[15];
  const float* linW = (const float*)d_in[16];
  const float* linb = (const float*)d_in[17];

  const int N = in_sizes[0] / 4;
  const int E = in_sizes[2] / 2;
  const int T = out_size / (N * 4);
  const int* src = eidx;
  const int* dst = eidx + E;

  size_t off = 0;
  auto alloc = [&](size_t bytes) -> void* {
    void* p = (char*)d_ws + off;
    off += (bytes + 511) & ~(size_t)511;
    return p;
  };
  int*   cnt     = (int*)alloc((size_t)N * 4);
  int*   row_ptr = (int*)alloc((size_t)(N + 1) * 4);
  int*   cursor  = (int*)alloc((size_t)N * 4);
  int*   col     = (int*)alloc((size_t)E * 4);
  float* rdeg    = (float*)alloc((size_t)N * 4);
  float* xprev   = (float*)alloc((size_t)N * 4 * 4);
  float* xcat    = (float*)alloc((size_t)N * 12 * 4);
  float* agg12b  = (float*)alloc((size_t)N * 12 * 4);
  unsigned short* h1   = (unsigned short*)alloc((size_t)N * 128 * 2);
  unsigned short* h2   = (unsigned short*)alloc((size_t)N * 128 * 2);
  unsigned short* aggb = (unsigned short*)alloc((size_t)N * 128 * 2);
  unsigned short* wb   = (unsigned short*)alloc((size_t)6 * 128 * 128 * 2);
  unsigned short* e2Wlb = wb + 0 * 16384;
  unsigned short* e2Wrb = wb + 1 * 16384;
  unsigned short* d1Wlb = wb + 2 * 16384;
  unsigned short* d1Wrb = wb + 3 * 16384;
  unsigned short* d2Wlb = wb + 4 * 16384;
  unsigned short* d2Wrb = wb + 5 * 16384;

  float* outp = (float*)d_out;

  // ---- once per launch: CSR + weight conversion ----
  hipMemsetAsync(cnt, 0, (size_t)N * 4, stream);
  hipMemsetAsync(cursor, 0, (size_t)N * 4, stream);
  count_deg_kernel<<<(E + 255) / 256, 256, 0, stream>>>(dst, cnt, E);
  rdeg_kernel<<<(N + 255) / 256, 256, 0, stream>>>(cnt, rdeg, N);
  scan_kernel<<<1, 1024, 0, stream>>>(cnt, row_ptr, N);
  fill_csr_kernel<<<(E + 255) / 256, 256, 0, stream>>>(src, dst, row_ptr, cursor, col, E);

  f2bf_kernel<<<64, 256, 0, stream>>>(e2Wl, e2Wlb, 16384);
  f2bf_kernel<<<64, 256, 0, stream>>>(e2Wr, e2Wrb, 16384);
  f2bf_kernel<<<64, 256, 0, stream>>>(d1Wl, d1Wlb, 16384);
  f2bf_kernel<<<64, 256, 0, stream>>>(d1Wr, d1Wrb, 16384);
  f2bf_kernel<<<64, 256, 0, stream>>>(d2Wl, d2Wlb, 16384);
  f2bf_kernel<<<64, 256, 0, stream>>>(d2Wr, d2Wrb, 16384);

  hipMemcpyAsync(xprev, F0, (size_t)N * 4 * 4, hipMemcpyDeviceToDevice, stream);

  const int gAgg128 = (N * 16 + 255) / 256;
  const int gAgg12  = (N * 16 + 255) / 256;
  const int gGemm   = (N + 127) / 128;
  const int gGemm12 = (N + 15) / 16;
  const int gLin    = (N + 63) / 64;

  for (int t = 0; t < T; ++t) {
    build_xcat_kernel<<<(N * 12 + 255) / 256, 256, 0, stream>>>(xprev, mesh, xcat, N);
    agg12_kernel<<<gAgg12, 256, 0, stream>>>(xcat, agg12b, row_ptr, col, rdeg, N);
    gemm12_kernel<<<gGemm12, 256, 0, stream>>>(agg12b, xcat, e1Wl, e1Wr, e1bl, h1, N);

    agg128_kernel<<<gAgg128, 256, 0, stream>>>(h1, aggb, row_ptr, col, rdeg, N);
    gemm128_mfma_kernel<<<gGemm, 256, 0, stream>>>(aggb, h1, e2Wlb, e2Wrb, e2bl, h2, N);

    agg128_kernel<<<gAgg128, 256, 0, stream>>>(h2, aggb, row_ptr, col, rdeg, N);
    gemm128_mfma_kernel<<<gGemm, 256, 0, stream>>>(aggb, h2, d1Wlb, d1Wrb, d1bl, h1, N);

    agg128_kernel<<<gAgg128, 256, 0, stream>>>(h1, aggb, row_ptr, col, rdeg, N);
    gemm128_mfma_kernel<<<gGemm, 256, 0, stream>>>(aggb, h1, d2Wlb, d2Wrb, d2bl, h2, N);

    lin_kernel<<<gLin, 256, 0, stream>>>(h2, linW, linb, xprev, outp, N, T, t);
  }
}

// Round 3
// 1734.886 us; speedup vs baseline: 1.9860x; 1.1605x over previous
//
#include <hip/hip_runtime.h>

// ---------------------------------------------------------------------------
// Recurrent GraphSAGE net. Round 2:
//  - agg128: unroll-4 gather (4 loads in flight) for L3 latency hiding
//  - enc1: build_xcat + agg12 fused into gemm12 (reads xprev/mesh directly)
//  - dec2: head (x_prev + h@linW^T + linb) fused into the MFMA GEMM epilogue
//  - coalesced 3-kernel scan, single f2bf conversion kernel
// Per timestep: enc1, [agg, gemm] x2, [agg, gemm+head]  = 7 dispatches.
// ---------------------------------------------------------------------------

typedef __attribute__((ext_vector_type(8))) short short8;
typedef __attribute__((ext_vector_type(8))) unsigned short ushort8;
typedef __attribute__((ext_vector_type(4))) float f32x4;

static __device__ __forceinline__ float b2f(unsigned short u) {
  return __uint_as_float(((unsigned int)u) << 16);
}
static __device__ __forceinline__ unsigned short f2bf(float f) {
  unsigned int u = __float_as_uint(f);
  u += 0x7FFFu + ((u >> 16) & 1u);   // round-nearest-even
  return (unsigned short)(u >> 16);
}

// ---------------- graph preprocessing ----------------

__global__ void count_deg_kernel(const int* __restrict__ dst, int* __restrict__ cnt, int E) {
  int e = blockIdx.x * blockDim.x + threadIdx.x;
  if (e < E) atomicAdd(&cnt[dst[e]], 1);
}

// coalesced 3-phase scan: blocksum -> scan sums -> expand (also emits rdeg)
__global__ __launch_bounds__(256) void blocksum_kernel(const int* __restrict__ cnt,
                                                       int* __restrict__ bsum, int n) {
  __shared__ int s[256];
  int tid = threadIdx.x;
  int i = blockIdx.x * 256 + tid;
  s[tid] = (i < n) ? cnt[i] : 0;
  __syncthreads();
  for (int off = 128; off > 0; off >>= 1) {
    if (tid < off) s[tid] += s[tid + off];
    __syncthreads();
  }
  if (tid == 0) bsum[blockIdx.x] = s[0];
}

__global__ __launch_bounds__(256) void scan_sums_kernel(const int* __restrict__ bsum,
                                                        int* __restrict__ boff, int nb) {
  __shared__ int s[256];
  int tid = threadIdx.x;
  int v = (tid < nb) ? bsum[tid] : 0;
  s[tid] = v;
  __syncthreads();
  for (int off = 1; off < 256; off <<= 1) {
    int t = (tid >= off) ? s[tid - off] : 0;
    __syncthreads();
    s[tid] += t;
    __syncthreads();
  }
  if (tid < nb) boff[tid] = s[tid] - v;   // exclusive
}

__global__ __launch_bounds__(256) void expand_kernel(const int* __restrict__ cnt,
                                                     const int* __restrict__ boff,
                                                     int* __restrict__ row_ptr,
                                                     float* __restrict__ rdeg, int n) {
  __shared__ int s[256];
  int tid = threadIdx.x;
  int i = blockIdx.x * 256 + tid;
  int v = (i < n) ? cnt[i] : 0;
  s[tid] = v;
  __syncthreads();
  for (int off = 1; off < 256; off <<= 1) {
    int t = (tid >= off) ? s[tid - off] : 0;
    __syncthreads();
    s[tid] += t;
    __syncthreads();
  }
  if (i < n) {
    row_ptr[i + 1] = boff[blockIdx.x] + s[tid];
    rdeg[i] = 1.0f / fmaxf((float)v, 1.0f);
  }
  if (i == 0) row_ptr[0] = 0;
}

__global__ void fill_csr_kernel(const int* __restrict__ src, const int* __restrict__ dst,
                                const int* __restrict__ row_ptr, int* __restrict__ cursor,
                                int* __restrict__ col, int E) {
  int e = blockIdx.x * blockDim.x + threadIdx.x;
  if (e < E) {
    int d = dst[e];
    int p = atomicAdd(&cursor[d], 1);
    col[row_ptr[d] + p] = src[e];
  }
}

// convert all 6 conv weight matrices (128x128 each) in one dispatch
__global__ void f2bf6_kernel(const float* __restrict__ s0, const float* __restrict__ s1,
                             const float* __restrict__ s2, const float* __restrict__ s3,
                             const float* __restrict__ s4, const float* __restrict__ s5,
                             unsigned short* __restrict__ dst) {
  int i = blockIdx.x * blockDim.x + threadIdx.x;
  if (i >= 6 * 16384) return;
  int m = i >> 14, o = i & 16383;
  const float* s;
  switch (m) {
    case 0: s = s0; break; case 1: s = s1; break; case 2: s = s2; break;
    case 3: s = s3; break; case 4: s = s4; break; default: s = s5; break;
  }
  dst[i] = f2bf(s[o]);
}

// ---------------- per-timestep kernels ----------------

// enc1: fused xcat-build + agg12 + GEMM (K=24, fp32), bf16 out. 16 nodes/block.
__global__ __launch_bounds__(256) void enc1_kernel(
    const float* __restrict__ xprev, const float* __restrict__ mesh,
    const int* __restrict__ row_ptr, const int* __restrict__ col,
    const float* __restrict__ rdeg,
    const float* __restrict__ Wl, const float* __restrict__ Wr,
    const float* __restrict__ bl, unsigned short* __restrict__ out, int N) {
  __shared__ float Ws[24][128];
  __shared__ float As[16][24];
  int tid = threadIdx.x;
  int nb = blockIdx.x * 16;
  for (int i = tid; i < 1536; i += 256) {
    int o = i / 12, k = i % 12;
    Ws[k][o] = Wl[i];
    Ws[12 + k][o] = Wr[i];
  }
  if (tid < 192) {
    int n = tid / 12, k = tid % 12;
    int gn = nb + n; if (gn > N - 1) gn = N - 1;
    // own feature
    float own = (k < 4) ? xprev[gn * 4 + k] : mesh[gn * 8 + (k - 4)];
    As[n][12 + k] = own;
    // mean aggregate of neighbors, channel k
    int j0 = row_ptr[gn], j1 = row_ptr[gn + 1];
    float acc = 0.0f;
    int j = j0;
    for (; j + 2 <= j1; j += 2) {
      int s0 = col[j], s1 = col[j + 1];
      float v0 = (k < 4) ? xprev[s0 * 4 + k] : mesh[s0 * 8 + (k - 4)];
      float v1 = (k < 4) ? xprev[s1 * 4 + k] : mesh[s1 * 8 + (k - 4)];
      acc += v0 + v1;
    }
    if (j < j1) {
      int s0 = col[j];
      acc += (k < 4) ? xprev[s0 * 4 + k] : mesh[s0 * 8 + (k - 4)];
    }
    As[n][k] = acc * rdeg[gn];
  }
  __syncthreads();
  int nl = tid >> 4;
  int og = tid & 15;
  float acc[8] = {};
#pragma unroll
  for (int k = 0; k < 24; ++k) {
    float a = As[nl][k];
    float4 w0 = *(const float4*)&Ws[k][og * 8];
    float4 w1 = *(const float4*)&Ws[k][og * 8 + 4];
    acc[0] += a * w0.x; acc[1] += a * w0.y; acc[2] += a * w0.z; acc[3] += a * w0.w;
    acc[4] += a * w1.x; acc[5] += a * w1.y; acc[6] += a * w1.z; acc[7] += a * w1.w;
  }
  int gn = nb + nl;
  if (gn < N) {
#pragma unroll
    for (int j = 0; j < 8; ++j) {
      float v = acc[j] + bl[og * 8 + j];
      out[gn * 128 + og * 8 + j] = f2bf(fmaxf(v, 0.0f));
    }
  }
}

// bf16 mean-aggregate: 16 lanes/node, ushort8/lane, unroll-4 (4 loads in flight)
__global__ void agg128_kernel(const unsigned short* __restrict__ feat,
                              unsigned short* __restrict__ out,
                              const int* __restrict__ row_ptr, const int* __restrict__ col,
                              const float* __restrict__ rdeg, int N) {
  int g = blockIdx.x * blockDim.x + threadIdx.x;
  int node = g >> 4;
  int d = g & 15;
  if (node >= N) return;
  int j0 = row_ptr[node], j1 = row_ptr[node + 1];
  float acc[8] = {};
  int j = j0;
  for (; j + 4 <= j1; j += 4) {
    int s0 = col[j], s1 = col[j + 1], s2 = col[j + 2], s3 = col[j + 3];
    ushort8 v0 = *(const ushort8*)&feat[s0 * 128 + d * 8];
    ushort8 v1 = *(const ushort8*)&feat[s1 * 128 + d * 8];
    ushort8 v2 = *(const ushort8*)&feat[s2 * 128 + d * 8];
    ushort8 v3 = *(const ushort8*)&feat[s3 * 128 + d * 8];
#pragma unroll
    for (int r = 0; r < 8; ++r)
      acc[r] += (b2f(v0[r]) + b2f(v1[r])) + (b2f(v2[r]) + b2f(v3[r]));
  }
  for (; j < j1; ++j) {
    ushort8 v0 = *(const ushort8*)&feat[col[j] * 128 + d * 8];
#pragma unroll
    for (int r = 0; r < 8; ++r) acc[r] += b2f(v0[r]);
  }
  float rd = rdeg[node];
  ushort8 o;
#pragma unroll
  for (int r = 0; r < 8; ++r) o[r] = f2bf(acc[r] * rd);
  *(ushort8*)&out[node * 128 + d * 8] = o;
}

// conv GEMM via MFMA: out = relu([agg|x] @ [Wl;Wr]^T + bl), bf16 in/out
__global__ __launch_bounds__(256) void gemm128_mfma_kernel(
    const unsigned short* __restrict__ agg, const unsigned short* __restrict__ x,
    const unsigned short* __restrict__ Wlb, const unsigned short* __restrict__ Wrb,
    const float* __restrict__ bl, unsigned short* __restrict__ out, int N) {
  int tid = threadIdx.x;
  int wave = tid >> 6;
  int lane = tid & 63;
  int nb = blockIdx.x * 128 + wave * 32;
  int l15 = lane & 15;
  int lk = (lane >> 4) * 8;

  f32x4 acc[2][8] = {};
  int r0 = nb + l15;      if (r0 > N - 1) r0 = N - 1;
  int r1 = nb + 16 + l15; if (r1 > N - 1) r1 = N - 1;

#pragma unroll
  for (int ks = 0; ks < 8; ++ks) {
    const unsigned short* As = (ks < 4) ? agg : x;
    const unsigned short* Ws = (ks < 4) ? Wlb : Wrb;
    int ko = (ks & 3) * 32 + lk;
    short8 a0 = *(const short8*)&As[r0 * 128 + ko];
    short8 a1 = *(const short8*)&As[r1 * 128 + ko];
#pragma unroll
    for (int ot = 0; ot < 8; ++ot) {
      short8 b = *(const short8*)&Ws[(ot * 16 + l15) * 128 + ko];
      acc[0][ot] = __builtin_amdgcn_mfma_f32_16x16x32_bf16(a0, b, acc[0][ot], 0, 0, 0);
      acc[1][ot] = __builtin_amdgcn_mfma_f32_16x16x32_bf16(a1, b, acc[1][ot], 0, 0, 0);
    }
  }

  int crow = (lane >> 4) * 4;
#pragma unroll
  for (int ot = 0; ot < 8; ++ot) {
    int gcol = ot * 16 + l15;
    float bv = bl[gcol];
#pragma unroll
    for (int mt = 0; mt < 2; ++mt) {
#pragma unroll
      for (int r = 0; r < 4; ++r) {
        int grow = nb + mt * 16 + crow + r;
        if (grow < N) {
          float v = fmaxf(acc[mt][ot][r] + bv, 0.0f);
          out[grow * 128 + gcol] = f2bf(v);
        }
      }
    }
  }
}

// dec2 GEMM + fused head: h = relu([agg|x]@[Wl;Wr]^T + bl);
// x_new = xprev + h@linW^T + linb; write out[:,t,:] and xprev. No h to memory.
__global__ __launch_bounds__(256) void gemm128_head_mfma_kernel(
    const unsigned short* __restrict__ agg, const unsigned short* __restrict__ x,
    const unsigned short* __restrict__ Wlb, const unsigned short* __restrict__ Wrb,
    const float* __restrict__ bl, const float* __restrict__ linW,
    const float* __restrict__ linb, float* __restrict__ xprev,
    float* __restrict__ out, int N, int T, int t) {
  __shared__ float Wh[4][128];
  int tid = threadIdx.x;
  for (int i = tid; i < 512; i += 256) Wh[i >> 7][i & 127] = linW[i];
  __syncthreads();

  int wave = tid >> 6;
  int lane = tid & 63;
  int nb = blockIdx.x * 128 + wave * 32;
  int l15 = lane & 15;
  int lk = (lane >> 4) * 8;

  f32x4 acc[2][8] = {};
  int r0 = nb + l15;      if (r0 > N - 1) r0 = N - 1;
  int r1 = nb + 16 + l15; if (r1 > N - 1) r1 = N - 1;

#pragma unroll
  for (int ks = 0; ks < 8; ++ks) {
    const unsigned short* As = (ks < 4) ? agg : x;
    const unsigned short* Ws = (ks < 4) ? Wlb : Wrb;
    int ko = (ks & 3) * 32 + lk;
    short8 a0 = *(const short8*)&As[r0 * 128 + ko];
    short8 a1 = *(const short8*)&As[r1 * 128 + ko];
#pragma unroll
    for (int ot = 0; ot < 8; ++ot) {
      short8 b = *(const short8*)&Ws[(ot * 16 + l15) * 128 + ko];
      acc[0][ot] = __builtin_amdgcn_mfma_f32_16x16x32_bf16(a0, b, acc[0][ot], 0, 0, 0);
      acc[1][ot] = __builtin_amdgcn_mfma_f32_16x16x32_bf16(a1, b, acc[1][ot], 0, 0, 0);
    }
  }

  // head: part[mt][r][o] = sum_col relu(h) * linW[o][col], col = ot*16+l15
  float part[2][4][4] = {};
#pragma unroll
  for (int ot = 0; ot < 8; ++ot) {
    int gcol = ot * 16 + l15;
    float bv = bl[gcol];
    float w0 = Wh[0][gcol], w1 = Wh[1][gcol], w2 = Wh[2][gcol], w3 = Wh[3][gcol];
#pragma unroll
    for (int mt = 0; mt < 2; ++mt)
#pragma unroll
      for (int r = 0; r < 4; ++r) {
        float hv = fmaxf(acc[mt][ot][r] + bv, 0.0f);
        part[mt][r][0] += hv * w0;
        part[mt][r][1] += hv * w1;
        part[mt][r][2] += hv * w2;
        part[mt][r][3] += hv * w3;
      }
  }
  // reduce across the 16 lanes of each row group (xor stays within group)
#pragma unroll
  for (int m = 1; m < 16; m <<= 1)
#pragma unroll
    for (int mt = 0; mt < 2; ++mt)
#pragma unroll
      for (int r = 0; r < 4; ++r)
#pragma unroll
        for (int o = 0; o < 4; ++o)
          part[mt][r][o] += __shfl_xor(part[mt][r][o], m, 64);

  if (l15 == 0) {
    int crow = (lane >> 4) * 4;
    float4 lb = *(const float4*)linb;
#pragma unroll
    for (int mt = 0; mt < 2; ++mt)
#pragma unroll
      for (int r = 0; r < 4; ++r) {
        int grow = nb + mt * 16 + crow + r;
        if (grow < N) {
          float4 xp = *(const float4*)&xprev[grow * 4];
          float4 xn;
          xn.x = xp.x + part[mt][r][0] + lb.x;
          xn.y = xp.y + part[mt][r][1] + lb.y;
          xn.z = xp.z + part[mt][r][2] + lb.z;
          xn.w = xp.w + part[mt][r][3] + lb.w;
          *(float4*)&out[(grow * T + t) * 4] = xn;
          *(float4*)&xprev[grow * 4] = xn;
        }
      }
  }
}

extern "C" void kernel_launch(void* const* d_in, const int* in_sizes, int n_in,
                              void* d_out, int out_size, void* d_ws, size_t ws_size,
                              hipStream_t stream) {
  const float* F0   = (const float*)d_in[0];
  const float* mesh = (const float*)d_in[1];
  const int*   eidx = (const int*)d_in[2];
  const float* e1Wl = (const float*)d_in[4];
  const float* e1bl = (const float*)d_in[5];
  const float* e1Wr = (const float*)d_in[6];
  const float* e2Wl = (const float*)d_in[7];
  const float* e2bl = (const float*)d_in[8];
  const float* e2Wr = (const float*)d_in[9];
  const float* d1Wl = (const float*)d_in[10];
  const float* d1bl = (const float*)d_in[11];
  const float* d1Wr = (const float*)d_in[12];
  const float* d2Wl = (const float*)d_in[13];
  const float* d2bl = (const float*)d_in[14];
  const float* d2Wr = (const float*)d_in[15];
  const float* linW = (const float*)d_in[16];
  const float* linb = (const float*)d_in[17];

  const int N = in_sizes[0] / 4;
  const int E = in_sizes[2] / 2;
  const int T = out_size / (N * 4);
  const int* src = eidx;
  const int* dst = eidx + E;

  size_t off = 0;
  auto alloc = [&](size_t bytes) -> void* {
    void* p = (char*)d_ws + off;
    off += (bytes + 511) & ~(size_t)511;
    return p;
  };
  int*   cnt     = (int*)alloc((size_t)N * 4);
  int*   row_ptr = (int*)alloc((size_t)(N + 1) * 4);
  int*   cursor  = (int*)alloc((size_t)N * 4);
  int*   col     = (int*)alloc((size_t)E * 4);
  float* rdeg    = (float*)alloc((size_t)N * 4);
  float* xprev   = (float*)alloc((size_t)N * 4 * 4);
  int*   bsum    = (int*)alloc(256 * 4);
  int*   boff    = (int*)alloc(256 * 4);
  unsigned short* h1   = (unsigned short*)alloc((size_t)N * 128 * 2);
  unsigned short* h2   = (unsigned short*)alloc((size_t)N * 128 * 2);
  unsigned short* aggb = (unsigned short*)alloc((size_t)N * 128 * 2);
  unsigned short* wb   = (unsigned short*)alloc((size_t)6 * 128 * 128 * 2);
  unsigned short* e2Wlb = wb + 0 * 16384;
  unsigned short* e2Wrb = wb + 1 * 16384;
  unsigned short* d1Wlb = wb + 2 * 16384;
  unsigned short* d1Wrb = wb + 3 * 16384;
  unsigned short* d2Wlb = wb + 4 * 16384;
  unsigned short* d2Wrb = wb + 5 * 16384;

  float* outp = (float*)d_out;

  const int NB = (N + 255) / 256;   // 196 <= 256

  // ---- once per launch: CSR + weight conversion ----
  hipMemsetAsync(cnt, 0, (size_t)N * 4, stream);
  hipMemsetAsync(cursor, 0, (size_t)N * 4, stream);
  count_deg_kernel<<<(E + 255) / 256, 256, 0, stream>>>(dst, cnt, E);
  blocksum_kernel<<<NB, 256, 0, stream>>>(cnt, bsum, N);
  scan_sums_kernel<<<1, 256, 0, stream>>>(bsum, boff, NB);
  expand_kernel<<<NB, 256, 0, stream>>>(cnt, boff, row_ptr, rdeg, N);
  fill_csr_kernel<<<(E + 255) / 256, 256, 0, stream>>>(src, dst, row_ptr, cursor, col, E);
  f2bf6_kernel<<<(6 * 16384 + 255) / 256, 256, 0, stream>>>(
      e2Wl, e2Wr, d1Wl, d1Wr, d2Wl, d2Wr, wb);
  hipMemcpyAsync(xprev, F0, (size_t)N * 4 * 4, hipMemcpyDeviceToDevice, stream);

  const int gAgg  = (N * 16 + 255) / 256;
  const int gGemm = (N + 127) / 128;
  const int gEnc1 = (N + 15) / 16;

  for (int t = 0; t < T; ++t) {
    enc1_kernel<<<gEnc1, 256, 0, stream>>>(xprev, mesh, row_ptr, col, rdeg,
                                           e1Wl, e1Wr, e1bl, h1, N);

    agg128_kernel<<<gAgg, 256, 0, stream>>>(h1, aggb, row_ptr, col, rdeg, N);
    gemm128_mfma_kernel<<<gGemm, 256, 0, stream>>>(aggb, h1, e2Wlb, e2Wrb, e2bl, h2, N);

    agg128_kernel<<<gAgg, 256, 0, stream>>>(h2, aggb, row_ptr, col, rdeg, N);
    gemm128_mfma_kernel<<<gGemm, 256, 0, stream>>>(aggb, h2, d1Wlb, d1Wrb, d1bl, h1, N);

    agg128_kernel<<<gAgg, 256, 0, stream>>>(h1, aggb, row_ptr, col, rdeg, N);
    gemm128_head_mfma_kernel<<<gGemm, 256, 0, stream>>>(aggb, h1, d2Wlb, d2Wrb, d2bl,
                                                        linW, linb, xprev, outp, N, T, t);
  }
}

// Round 4
// 1642.397 us; speedup vs baseline: 2.0979x; 1.0563x over previous
//
#include <hip/hip_runtime.h>

// ---------------------------------------------------------------------------
// Recurrent GraphSAGE net. Round 3:
//  - mesh contribution of enc1 precomputed once per launch (timestep-invariant):
//      mterm = Wl[:,4:12]@agg(mesh) + Wr[:,4:12]@mesh + bl   (N x 128, bf16)
//    per-step enc1 = float4 gather of xprev (16B/edge) + K=8 GEMM + mterm
//  - agg128: unroll-8 (8 x 16B loads in flight) for L3 latency hiding
//  - CSR fill without atomics (rank recorded during count pass)
// ---------------------------------------------------------------------------

typedef __attribute__((ext_vector_type(8))) short short8;
typedef __attribute__((ext_vector_type(8))) unsigned short ushort8;
typedef __attribute__((ext_vector_type(4))) float f32x4;

static __device__ __forceinline__ float b2f(unsigned short u) {
  return __uint_as_float(((unsigned int)u) << 16);
}
static __device__ __forceinline__ unsigned short f2bf(float f) {
  unsigned int u = __float_as_uint(f);
  u += 0x7FFFu + ((u >> 16) & 1u);   // round-nearest-even
  return (unsigned short)(u >> 16);
}

// ---------------- graph preprocessing ----------------

__global__ void count_rank_kernel(const int* __restrict__ dst, int* __restrict__ cnt,
                                  int* __restrict__ rank, int E) {
  int e = blockIdx.x * blockDim.x + threadIdx.x;
  if (e < E) rank[e] = atomicAdd(&cnt[dst[e]], 1);
}

__global__ __launch_bounds__(256) void blocksum_kernel(const int* __restrict__ cnt,
                                                       int* __restrict__ bsum, int n) {
  __shared__ int s[256];
  int tid = threadIdx.x;
  int i = blockIdx.x * 256 + tid;
  s[tid] = (i < n) ? cnt[i] : 0;
  __syncthreads();
  for (int off = 128; off > 0; off >>= 1) {
    if (tid < off) s[tid] += s[tid + off];
    __syncthreads();
  }
  if (tid == 0) bsum[blockIdx.x] = s[0];
}

__global__ __launch_bounds__(256) void scan_sums_kernel(const int* __restrict__ bsum,
                                                        int* __restrict__ boff, int nb) {
  __shared__ int s[256];
  int tid = threadIdx.x;
  int v = (tid < nb) ? bsum[tid] : 0;
  s[tid] = v;
  __syncthreads();
  for (int off = 1; off < 256; off <<= 1) {
    int t = (tid >= off) ? s[tid - off] : 0;
    __syncthreads();
    s[tid] += t;
    __syncthreads();
  }
  if (tid < nb) boff[tid] = s[tid] - v;   // exclusive
}

__global__ __launch_bounds__(256) void expand_kernel(const int* __restrict__ cnt,
                                                     const int* __restrict__ boff,
                                                     int* __restrict__ row_ptr,
                                                     float* __restrict__ rdeg, int n) {
  __shared__ int s[256];
  int tid = threadIdx.x;
  int i = blockIdx.x * 256 + tid;
  int v = (i < n) ? cnt[i] : 0;
  s[tid] = v;
  __syncthreads();
  for (int off = 1; off < 256; off <<= 1) {
    int t = (tid >= off) ? s[tid - off] : 0;
    __syncthreads();
    s[tid] += t;
    __syncthreads();
  }
  if (i < n) {
    row_ptr[i + 1] = boff[blockIdx.x] + s[tid];
    rdeg[i] = 1.0f / fmaxf((float)v, 1.0f);
  }
  if (i == 0) row_ptr[0] = 0;
}

// no atomics: slot position = row_ptr[dst] + rank (recorded during count)
__global__ void fill_csr2_kernel(const int* __restrict__ src, const int* __restrict__ dst,
                                 const int* __restrict__ rank, const int* __restrict__ row_ptr,
                                 int* __restrict__ col, int E) {
  int e = blockIdx.x * blockDim.x + threadIdx.x;
  if (e < E) col[row_ptr[dst[e]] + rank[e]] = src[e];
}

// convert all 6 conv weight matrices (128x128 each) in one dispatch
__global__ void f2bf6_kernel(const float* __restrict__ s0, const float* __restrict__ s1,
                             const float* __restrict__ s2, const float* __restrict__ s3,
                             const float* __restrict__ s4, const float* __restrict__ s5,
                             unsigned short* __restrict__ dst) {
  int i = blockIdx.x * blockDim.x + threadIdx.x;
  if (i >= 6 * 16384) return;
  int m = i >> 14, o = i & 16383;
  const float* s;
  switch (m) {
    case 0: s = s0; break; case 1: s = s1; break; case 2: s = s2; break;
    case 3: s = s3; break; case 4: s = s4; break; default: s = s5; break;
  }
  dst[i] = f2bf(s[o]);
}

// mean-aggregate mesh (8 fp32 ch): 2 lanes/node, float4/lane, once per launch
__global__ void aggmesh_kernel(const float* __restrict__ mesh, float* __restrict__ aggm,
                               const int* __restrict__ row_ptr, const int* __restrict__ col,
                               const float* __restrict__ rdeg, int N) {
  int g = blockIdx.x * blockDim.x + threadIdx.x;
  int node = g >> 1, h = (g & 1) * 4;
  if (node >= N) return;
  int j0 = row_ptr[node], j1 = row_ptr[node + 1];
  float4 acc = make_float4(0.f, 0.f, 0.f, 0.f);
  int j = j0;
  for (; j + 4 <= j1; j += 4) {
    float4 v0 = *(const float4*)&mesh[col[j] * 8 + h];
    float4 v1 = *(const float4*)&mesh[col[j + 1] * 8 + h];
    float4 v2 = *(const float4*)&mesh[col[j + 2] * 8 + h];
    float4 v3 = *(const float4*)&mesh[col[j + 3] * 8 + h];
    acc.x += (v0.x + v1.x) + (v2.x + v3.x);
    acc.y += (v0.y + v1.y) + (v2.y + v3.y);
    acc.z += (v0.z + v1.z) + (v2.z + v3.z);
    acc.w += (v0.w + v1.w) + (v2.w + v3.w);
  }
  for (; j < j1; ++j) {
    float4 v0 = *(const float4*)&mesh[col[j] * 8 + h];
    acc.x += v0.x; acc.y += v0.y; acc.z += v0.z; acc.w += v0.w;
  }
  float r = rdeg[node];
  acc.x *= r; acc.y *= r; acc.z *= r; acc.w *= r;
  *(float4*)&aggm[node * 8 + h] = acc;
}

// mterm[n][o] = bl[o] + sum_k Wl[o][4+k]*aggm[n][k] + Wr[o][4+k]*mesh[n][k]
__global__ void mesh_term_kernel(const float* __restrict__ aggm, const float* __restrict__ mesh,
                                 const float* __restrict__ Wl, const float* __restrict__ Wr,
                                 const float* __restrict__ bl, unsigned short* __restrict__ mterm,
                                 int N) {
  int g = blockIdx.x * blockDim.x + threadIdx.x;
  if (g >= N * 128) return;
  int n = g >> 7, o = g & 127;
  float acc = bl[o];
#pragma unroll
  for (int k = 0; k < 8; ++k)
    acc += Wl[o * 12 + 4 + k] * aggm[n * 8 + k] + Wr[o * 12 + 4 + k] * mesh[n * 8 + k];
  mterm[g] = f2bf(acc);
}

// ---------------- per-timestep kernels ----------------

// enc1: gather xprev (float4 rows), K=8 GEMM, + mterm, relu -> bf16.
// 64 nodes/block; 4 threads per node for the gather; thread -> 32 outputs.
__global__ __launch_bounds__(256) void enc1_kernel(
    const float* __restrict__ xprev, const int* __restrict__ row_ptr,
    const int* __restrict__ col, const float* __restrict__ rdeg,
    const float* __restrict__ Wl, const float* __restrict__ Wr,
    const unsigned short* __restrict__ mterm, unsigned short* __restrict__ out, int N) {
  __shared__ float Wx[8][128];   // k<4: Wl[:, k]; k>=4: Wr[:, k-4]
  __shared__ float4 part[256];
  __shared__ float As[64][8];    // [node][aggx(4) | own(4)]
  int tid = threadIdx.x;
  int nb = blockIdx.x * 64;
  for (int i = tid; i < 1024; i += 256) {
    int k = i >> 7, o = i & 127;
    Wx[k][o] = (k < 4) ? Wl[o * 12 + k] : Wr[o * 12 + (k - 4)];
  }
  int nl = tid >> 2, q = tid & 3;
  int gn = nb + nl; if (gn > N - 1) gn = N - 1;
  int j0 = row_ptr[gn], j1 = row_ptr[gn + 1];
  int per = (j1 - j0 + 3) >> 2;
  int a = j0 + q * per; if (a > j1) a = j1;
  int b = a + per; if (b > j1) b = j1;
  float4 acc = make_float4(0.f, 0.f, 0.f, 0.f);
  int j = a;
  for (; j + 2 <= b; j += 2) {
    float4 v0 = *(const float4*)&xprev[col[j] * 4];
    float4 v1 = *(const float4*)&xprev[col[j + 1] * 4];
    acc.x += v0.x + v1.x; acc.y += v0.y + v1.y;
    acc.z += v0.z + v1.z; acc.w += v0.w + v1.w;
  }
  if (j < b) {
    float4 v0 = *(const float4*)&xprev[col[j] * 4];
    acc.x += v0.x; acc.y += v0.y; acc.z += v0.z; acc.w += v0.w;
  }
  part[tid] = acc;
  __syncthreads();
  if (tid < 64) {
    int g2 = nb + tid; if (g2 > N - 1) g2 = N - 1;
    float4 s0 = part[tid * 4], s1 = part[tid * 4 + 1];
    float4 s2 = part[tid * 4 + 2], s3 = part[tid * 4 + 3];
    float r = rdeg[g2];
    As[tid][0] = (s0.x + s1.x + s2.x + s3.x) * r;
    As[tid][1] = (s0.y + s1.y + s2.y + s3.y) * r;
    As[tid][2] = (s0.z + s1.z + s2.z + s3.z) * r;
    As[tid][3] = (s0.w + s1.w + s2.w + s3.w) * r;
    float4 own = *(const float4*)&xprev[g2 * 4];
    As[tid][4] = own.x; As[tid][5] = own.y; As[tid][6] = own.z; As[tid][7] = own.w;
  }
  __syncthreads();
  int gn2 = nb + nl;
  if (gn2 >= N) return;
  float av[8];
#pragma unroll
  for (int k = 0; k < 8; ++k) av[k] = As[nl][k];
  int o0 = q * 32;
#pragma unroll
  for (int c = 0; c < 4; ++c) {
    ushort8 mt = *(const ushort8*)&mterm[gn2 * 128 + o0 + c * 8];
    ushort8 ov;
#pragma unroll
    for (int oo = 0; oo < 8; ++oo) {
      int o = o0 + c * 8 + oo;
      float s = b2f(mt[oo]);
#pragma unroll
      for (int k = 0; k < 8; ++k) s += av[k] * Wx[k][o];
      ov[oo] = f2bf(fmaxf(s, 0.0f));
    }
    *(ushort8*)&out[gn2 * 128 + o0 + c * 8] = ov;
  }
}

// bf16 mean-aggregate: 16 lanes/node, ushort8/lane, unroll-8 (8 loads in flight)
__global__ void agg128_kernel(const unsigned short* __restrict__ feat,
                              unsigned short* __restrict__ out,
                              const int* __restrict__ row_ptr, const int* __restrict__ col,
                              const float* __restrict__ rdeg, int N) {
  int g = blockIdx.x * blockDim.x + threadIdx.x;
  int node = g >> 4;
  int d = g & 15;
  if (node >= N) return;
  int j0 = row_ptr[node], j1 = row_ptr[node + 1];
  float acc[8] = {};
  int j = j0;
  for (; j + 8 <= j1; j += 8) {
    ushort8 v0 = *(const ushort8*)&feat[col[j    ] * 128 + d * 8];
    ushort8 v1 = *(const ushort8*)&feat[col[j + 1] * 128 + d * 8];
    ushort8 v2 = *(const ushort8*)&feat[col[j + 2] * 128 + d * 8];
    ushort8 v3 = *(const ushort8*)&feat[col[j + 3] * 128 + d * 8];
    ushort8 v4 = *(const ushort8*)&feat[col[j + 4] * 128 + d * 8];
    ushort8 v5 = *(const ushort8*)&feat[col[j + 5] * 128 + d * 8];
    ushort8 v6 = *(const ushort8*)&feat[col[j + 6] * 128 + d * 8];
    ushort8 v7 = *(const ushort8*)&feat[col[j + 7] * 128 + d * 8];
#pragma unroll
    for (int r = 0; r < 8; ++r)
      acc[r] += ((b2f(v0[r]) + b2f(v1[r])) + (b2f(v2[r]) + b2f(v3[r]))) +
                ((b2f(v4[r]) + b2f(v5[r])) + (b2f(v6[r]) + b2f(v7[r])));
  }
  for (; j + 2 <= j1; j += 2) {
    ushort8 v0 = *(const ushort8*)&feat[col[j] * 128 + d * 8];
    ushort8 v1 = *(const ushort8*)&feat[col[j + 1] * 128 + d * 8];
#pragma unroll
    for (int r = 0; r < 8; ++r) acc[r] += b2f(v0[r]) + b2f(v1[r]);
  }
  if (j < j1) {
    ushort8 v0 = *(const ushort8*)&feat[col[j] * 128 + d * 8];
#pragma unroll
    for (int r = 0; r < 8; ++r) acc[r] += b2f(v0[r]);
  }
  float rd = rdeg[node];
  ushort8 o;
#pragma unroll
  for (int r = 0; r < 8; ++r) o[r] = f2bf(acc[r] * rd);
  *(ushort8*)&out[node * 128 + d * 8] = o;
}

// conv GEMM via MFMA: out = relu([agg|x] @ [Wl;Wr]^T + bl), bf16 in/out
__global__ __launch_bounds__(256) void gemm128_mfma_kernel(
    const unsigned short* __restrict__ agg, const unsigned short* __restrict__ x,
    const unsigned short* __restrict__ Wlb, const unsigned short* __restrict__ Wrb,
    const float* __restrict__ bl, unsigned short* __restrict__ out, int N) {
  int tid = threadIdx.x;
  int wave = tid >> 6;
  int lane = tid & 63;
  int nb = blockIdx.x * 128 + wave * 32;
  int l15 = lane & 15;
  int lk = (lane >> 4) * 8;

  f32x4 acc[2][8] = {};
  int r0 = nb + l15;      if (r0 > N - 1) r0 = N - 1;
  int r1 = nb + 16 + l15; if (r1 > N - 1) r1 = N - 1;

#pragma unroll
  for (int ks = 0; ks < 8; ++ks) {
    const unsigned short* As = (ks < 4) ? agg : x;
    const unsigned short* Ws = (ks < 4) ? Wlb : Wrb;
    int ko = (ks & 3) * 32 + lk;
    short8 a0 = *(const short8*)&As[r0 * 128 + ko];
    short8 a1 = *(const short8*)&As[r1 * 128 + ko];
#pragma unroll
    for (int ot = 0; ot < 8; ++ot) {
      short8 b = *(const short8*)&Ws[(ot * 16 + l15) * 128 + ko];
      acc[0][ot] = __builtin_amdgcn_mfma_f32_16x16x32_bf16(a0, b, acc[0][ot], 0, 0, 0);
      acc[1][ot] = __builtin_amdgcn_mfma_f32_16x16x32_bf16(a1, b, acc[1][ot], 0, 0, 0);
    }
  }

  int crow = (lane >> 4) * 4;
#pragma unroll
  for (int ot = 0; ot < 8; ++ot) {
    int gcol = ot * 16 + l15;
    float bv = bl[gcol];
#pragma unroll
    for (int mt = 0; mt < 2; ++mt) {
#pragma unroll
      for (int r = 0; r < 4; ++r) {
        int grow = nb + mt * 16 + crow + r;
        if (grow < N) {
          float v = fmaxf(acc[mt][ot][r] + bv, 0.0f);
          out[grow * 128 + gcol] = f2bf(v);
        }
      }
    }
  }
}

// dec2 GEMM + fused head: h = relu([agg|x]@[Wl;Wr]^T + bl);
// x_new = xprev + h@linW^T + linb; write out[:,t,:] and xprev.
__global__ __launch_bounds__(256) void gemm128_head_mfma_kernel(
    const unsigned short* __restrict__ agg, const unsigned short* __restrict__ x,
    const unsigned short* __restrict__ Wlb, const unsigned short* __restrict__ Wrb,
    const float* __restrict__ bl, const float* __restrict__ linW,
    const float* __restrict__ linb, float* __restrict__ xprev,
    float* __restrict__ out, int N, int T, int t) {
  __shared__ float Wh[4][128];
  int tid = threadIdx.x;
  for (int i = tid; i < 512; i += 256) Wh[i >> 7][i & 127] = linW[i];
  __syncthreads();

  int wave = tid >> 6;
  int lane = tid & 63;
  int nb = blockIdx.x * 128 + wave * 32;
  int l15 = lane & 15;
  int lk = (lane >> 4) * 8;

  f32x4 acc[2][8] = {};
  int r0 = nb + l15;      if (r0 > N - 1) r0 = N - 1;
  int r1 = nb + 16 + l15; if (r1 > N - 1) r1 = N - 1;

#pragma unroll
  for (int ks = 0; ks < 8; ++ks) {
    const unsigned short* As = (ks < 4) ? agg : x;
    const unsigned short* Ws = (ks < 4) ? Wlb : Wrb;
    int ko = (ks & 3) * 32 + lk;
    short8 a0 = *(const short8*)&As[r0 * 128 + ko];
    short8 a1 = *(const short8*)&As[r1 * 128 + ko];
#pragma unroll
    for (int ot = 0; ot < 8; ++ot) {
      short8 b = *(const short8*)&Ws[(ot * 16 + l15) * 128 + ko];
      acc[0][ot] = __builtin_amdgcn_mfma_f32_16x16x32_bf16(a0, b, acc[0][ot], 0, 0, 0);
      acc[1][ot] = __builtin_amdgcn_mfma_f32_16x16x32_bf16(a1, b, acc[1][ot], 0, 0, 0);
    }
  }

  float part[2][4][4] = {};
#pragma unroll
  for (int ot = 0; ot < 8; ++ot) {
    int gcol = ot * 16 + l15;
    float bv = bl[gcol];
    float w0 = Wh[0][gcol], w1 = Wh[1][gcol], w2 = Wh[2][gcol], w3 = Wh[3][gcol];
#pragma unroll
    for (int mt = 0; mt < 2; ++mt)
#pragma unroll
      for (int r = 0; r < 4; ++r) {
        float hv = fmaxf(acc[mt][ot][r] + bv, 0.0f);
        part[mt][r][0] += hv * w0;
        part[mt][r][1] += hv * w1;
        part[mt][r][2] += hv * w2;
        part[mt][r][3] += hv * w3;
      }
  }
#pragma unroll
  for (int m = 1; m < 16; m <<= 1)
#pragma unroll
    for (int mt = 0; mt < 2; ++mt)
#pragma unroll
      for (int r = 0; r < 4; ++r)
#pragma unroll
        for (int o = 0; o < 4; ++o)
          part[mt][r][o] += __shfl_xor(part[mt][r][o], m, 64);

  if (l15 == 0) {
    int crow = (lane >> 4) * 4;
    float4 lb = *(const float4*)linb;
#pragma unroll
    for (int mt = 0; mt < 2; ++mt)
#pragma unroll
      for (int r = 0; r < 4; ++r) {
        int grow = nb + mt * 16 + crow + r;
        if (grow < N) {
          float4 xp = *(const float4*)&xprev[grow * 4];
          float4 xn;
          xn.x = xp.x + part[mt][r][0] + lb.x;
          xn.y = xp.y + part[mt][r][1] + lb.y;
          xn.z = xp.z + part[mt][r][2] + lb.z;
          xn.w = xp.w + part[mt][r][3] + lb.w;
          *(float4*)&out[(grow * T + t) * 4] = xn;
          *(float4*)&xprev[grow * 4] = xn;
        }
      }
  }
}

extern "C" void kernel_launch(void* const* d_in, const int* in_sizes, int n_in,
                              void* d_out, int out_size, void* d_ws, size_t ws_size,
                              hipStream_t stream) {
  const float* F0   = (const float*)d_in[0];
  const float* mesh = (const float*)d_in[1];
  const int*   eidx = (const int*)d_in[2];
  const float* e1Wl = (const float*)d_in[4];
  const float* e1bl = (const float*)d_in[5];
  const float* e1Wr = (const float*)d_in[6];
  const float* e2Wl = (const float*)d_in[7];
  const float* e2bl = (const float*)d_in[8];
  const float* e2Wr = (const float*)d_in[9];
  const float* d1Wl = (const float*)d_in[10];
  const float* d1bl = (const float*)d_in[11];
  const float* d1Wr = (const float*)d_in[12];
  const float* d2Wl = (const float*)d_in[13];
  const float* d2bl = (const float*)d_in[14];
  const float* d2Wr = (const float*)d_in[15];
  const float* linW = (const float*)d_in[16];
  const float* linb = (const float*)d_in[17];

  const int N = in_sizes[0] / 4;
  const int E = in_sizes[2] / 2;
  const int T = out_size / (N * 4);
  const int* src = eidx;
  const int* dst = eidx + E;

  size_t off = 0;
  auto alloc = [&](size_t bytes) -> void* {
    void* p = (char*)d_ws + off;
    off += (bytes + 511) & ~(size_t)511;
    return p;
  };
  int*   cnt     = (int*)alloc((size_t)N * 4);
  int*   row_ptr = (int*)alloc((size_t)(N + 1) * 4);
  int*   rank    = (int*)alloc((size_t)E * 4);
  int*   col     = (int*)alloc((size_t)E * 4);
  float* rdeg    = (float*)alloc((size_t)N * 4);
  float* xprev   = (float*)alloc((size_t)N * 4 * 4);
  float* aggm    = (float*)alloc((size_t)N * 8 * 4);
  int*   bsum    = (int*)alloc(256 * 4);
  int*   boff    = (int*)alloc(256 * 4);
  unsigned short* mterm = (unsigned short*)alloc((size_t)N * 128 * 2);
  unsigned short* h1   = (unsigned short*)alloc((size_t)N * 128 * 2);
  unsigned short* h2   = (unsigned short*)alloc((size_t)N * 128 * 2);
  unsigned short* aggb = (unsigned short*)alloc((size_t)N * 128 * 2);
  unsigned short* wb   = (unsigned short*)alloc((size_t)6 * 128 * 128 * 2);
  unsigned short* e2Wlb = wb + 0 * 16384;
  unsigned short* e2Wrb = wb + 1 * 16384;
  unsigned short* d1Wlb = wb + 2 * 16384;
  unsigned short* d1Wrb = wb + 3 * 16384;
  unsigned short* d2Wlb = wb + 4 * 16384;
  unsigned short* d2Wrb = wb + 5 * 16384;

  float* outp = (float*)d_out;

  const int NB = (N + 255) / 256;   // 196 <= 256

  // ---- once per launch: CSR + invariants ----
  hipMemsetAsync(cnt, 0, (size_t)N * 4, stream);
  count_rank_kernel<<<(E + 255) / 256, 256, 0, stream>>>(dst, cnt, rank, E);
  blocksum_kernel<<<NB, 256, 0, stream>>>(cnt, bsum, N);
  scan_sums_kernel<<<1, 256, 0, stream>>>(bsum, boff, NB);
  expand_kernel<<<NB, 256, 0, stream>>>(cnt, boff, row_ptr, rdeg, N);
  fill_csr2_kernel<<<(E + 255) / 256, 256, 0, stream>>>(src, dst, rank, row_ptr, col, E);
  f2bf6_kernel<<<(6 * 16384 + 255) / 256, 256, 0, stream>>>(
      e2Wl, e2Wr, d1Wl, d1Wr, d2Wl, d2Wr, wb);
  aggmesh_kernel<<<(N * 2 + 255) / 256, 256, 0, stream>>>(mesh, aggm, row_ptr, col, rdeg, N);
  mesh_term_kernel<<<(N * 128 + 255) / 256, 256, 0, stream>>>(aggm, mesh, e1Wl, e1Wr, e1bl,
                                                              mterm, N);
  hipMemcpyAsync(xprev, F0, (size_t)N * 4 * 4, hipMemcpyDeviceToDevice, stream);

  const int gAgg  = (N * 16 + 255) / 256;
  const int gGemm = (N + 127) / 128;
  const int gEnc1 = (N + 63) / 64;

  for (int t = 0; t < T; ++t) {
    enc1_kernel<<<gEnc1, 256, 0, stream>>>(xprev, row_ptr, col, rdeg,
                                           e1Wl, e1Wr, mterm, h1, N);

    agg128_kernel<<<gAgg, 256, 0, stream>>>(h1, aggb, row_ptr, col, rdeg, N);
    gemm128_mfma_kernel<<<gGemm, 256, 0, stream>>>(aggb, h1, e2Wlb, e2Wrb, e2bl, h2, N);

    agg128_kernel<<<gAgg, 256, 0, stream>>>(h2, aggb, row_ptr, col, rdeg, N);
    gemm128_mfma_kernel<<<gGemm, 256, 0, stream>>>(aggb, h2, d1Wlb, d1Wrb, d1bl, h1, N);

    agg128_kernel<<<gAgg, 256, 0, stream>>>(h1, aggb, row_ptr, col, rdeg, N);
    gemm128_head_mfma_kernel<<<gGemm, 256, 0, stream>>>(aggb, h1, d2Wlb, d2Wrb, d2bl,
                                                        linW, linb, xprev, outp, N, T, t);
  }
}